// Round 1
// baseline (2948.302 us; speedup 1.0000x reference)
//
#include <hip/hip_runtime.h>
#include <math.h>

// Problem constants (match reference)
constexpr int NG  = 100000;          // graphs
constexpr int NPG = 38;              // nodes per graph
constexpr int NN  = NG * NPG;        // 3,800,000 nodes
constexpr long long NE = 60800000LL; // edges

// ---------------------------------------------------------------------------
// Edge kernel: per edge e: msg = x[src[e]] * (edge_attr[e]*w + b);
//              atomicAdd(agg[dst[e]], msg)
// Vectorized x4 (NE % 4 == 0). Grid-stride.
// ---------------------------------------------------------------------------
__global__ void __launch_bounds__(256) edge_kernel(
    const float* __restrict__ x,
    const int*   __restrict__ ei,     // [2, NE] flat: first NE = src, next NE = dst
    const float* __restrict__ ea,     // [NE]
    const float* __restrict__ wptr,   // edge_nn_w (1)
    const float* __restrict__ bptr,   // edge_nn_b (1)
    float*       __restrict__ agg)    // [NN], pre-zeroed
{
    const float w = wptr[0];
    const float b = bptr[0];
    const int nvec = (int)(NE / 4);
    const int4*   src4 = (const int4*)ei;
    const int4*   dst4 = (const int4*)(ei + NE);
    const float4* ea4  = (const float4*)ea;
    const int stride = gridDim.x * blockDim.x;
    for (int i = blockIdx.x * blockDim.x + threadIdx.x; i < nvec; i += stride) {
        int4   s = src4[i];
        int4   d = dst4[i];
        float4 e = ea4[i];
        atomicAdd(&agg[d.x], x[s.x] * (e.x * w + b));
        atomicAdd(&agg[d.y], x[s.y] * (e.y * w + b));
        atomicAdd(&agg[d.z], x[s.z] * (e.z * w + b));
        atomicAdd(&agg[d.w], x[s.w] * (e.w * w + b));
    }
}

// ---------------------------------------------------------------------------
// Head kernel: 256 graphs per block. Stage nodes = x*cr + agg + cb into LDS
// with coalesced loads, then per-thread MLP 38 -> 4 -> 4 -> 1, sigmoid*11.
// ---------------------------------------------------------------------------
__global__ void __launch_bounds__(256) head_kernel(
    const float* __restrict__ x,
    const float* __restrict__ agg,
    const float* __restrict__ conv_root,
    const float* __restrict__ conv_bias,
    const float* __restrict__ W1, const float* __restrict__ b1,
    const float* __restrict__ W2, const float* __restrict__ b2,
    const float* __restrict__ W3, const float* __restrict__ b3,
    float* __restrict__ out)
{
    __shared__ float nv[256 * NPG];   // 38,912 B
    const float cr = conv_root[0];
    const float cb = conv_bias[0];

    const int gbase = blockIdx.x * 256;
    const int gcount = (NG - gbase < 256) ? (NG - gbase) : 256;
    const int fcount = gcount * NPG;
    const long long nbase = (long long)gbase * NPG;

    for (int k = threadIdx.x; k < fcount; k += 256) {
        long long gi = nbase + k;
        nv[k] = x[gi] * cr + agg[gi] + cb;
    }
    __syncthreads();

    const int g = gbase + threadIdx.x;
    if (g < NG) {
        const float* p = &nv[threadIdx.x * NPG];
        float h0 = b1[0], h1 = b1[1], h2 = b1[2], h3 = b1[3];
        #pragma unroll
        for (int j = 0; j < NPG; ++j) {
            float v = p[j];
            h0 += v * W1[j * 4 + 0];
            h1 += v * W1[j * 4 + 1];
            h2 += v * W1[j * 4 + 2];
            h3 += v * W1[j * 4 + 3];
        }
        h0 = fmaxf(h0, 0.f); h1 = fmaxf(h1, 0.f);
        h2 = fmaxf(h2, 0.f); h3 = fmaxf(h3, 0.f);

        float q0 = b2[0] + h0 * W2[0] + h1 * W2[4] + h2 * W2[8]  + h3 * W2[12];
        float q1 = b2[1] + h0 * W2[1] + h1 * W2[5] + h2 * W2[9]  + h3 * W2[13];
        float q2 = b2[2] + h0 * W2[2] + h1 * W2[6] + h2 * W2[10] + h3 * W2[14];
        float q3 = b2[3] + h0 * W2[3] + h1 * W2[7] + h2 * W2[11] + h3 * W2[15];
        q0 = fmaxf(q0, 0.f); q1 = fmaxf(q1, 0.f);
        q2 = fmaxf(q2, 0.f); q3 = fmaxf(q3, 0.f);

        float z = b3[0] + q0 * W3[0] + q1 * W3[1] + q2 * W3[2] + q3 * W3[3];
        float s = 1.0f / (1.0f + __expf(-z));
        out[g] = 11.0f * s;
    }
}

extern "C" void kernel_launch(void* const* d_in, const int* in_sizes, int n_in,
                              void* d_out, int out_size, void* d_ws, size_t ws_size,
                              hipStream_t stream) {
    const float* x         = (const float*)d_in[0];
    const int*   ei        = (const int*)  d_in[1];
    const float* ea        = (const float*)d_in[2];
    const float* conv_root = (const float*)d_in[3];
    const float* conv_bias = (const float*)d_in[4];
    const float* ew        = (const float*)d_in[5];
    const float* eb        = (const float*)d_in[6];
    const float* W1        = (const float*)d_in[7];
    const float* b1        = (const float*)d_in[8];
    const float* W2        = (const float*)d_in[9];
    const float* b2        = (const float*)d_in[10];
    const float* W3        = (const float*)d_in[11];
    const float* b3        = (const float*)d_in[12];

    float* agg = (float*)d_ws;        // NN floats = 15.2 MB scratch
    float* out = (float*)d_out;

    // agg must be zero every call (harness does not re-poison between replays)
    hipMemsetAsync(agg, 0, (size_t)NN * sizeof(float), stream);

    edge_kernel<<<2048, 256, 0, stream>>>(x, ei, ea, ew, eb, agg);

    const int hblocks = (NG + 255) / 256;
    head_kernel<<<hblocks, 256, 0, stream>>>(x, agg, conv_root, conv_bias,
                                             W1, b1, W2, b2, W3, b3, out);
}